// Round 8
// baseline (629.820 us; speedup 1.0000x reference)
//
#include <hip/hip_runtime.h>
#include <hip/hip_bf16.h>
#include <math.h>

// ---------------------------------------------------------------------------
// GraphAttentionLayer on MI355X — INSTRUMENTATION ROUND.
// Identical math/kernels to R7, except:
//   k0 launched with grid.y=2  (2x identical work, benign identical writes)
//   k5 launched with grid.z=4  (4x identical work, benign identical writes)
// Purpose: dur_us = base + 3*k5 + k0, and the replicated dispatches become
// long enough to surface in the profiler's top-5 WITH counters.
// ---------------------------------------------------------------------------

using f32x4  = __attribute__((ext_vector_type(4))) float;
using bf16x8 = __attribute__((ext_vector_type(8))) short;

#define N_NODES 8192
#define FIN     256
#define FOUT    128
#define NPAD    144
#define NSPLIT  8
#define KCHUNK  (N_NODES / NSPLIT)   // 1024

// workspace layout (bytes)
#define X_OFF    0u                                   // 8192*128 f32  = 4 MB
#define T_OFF    (X_OFF + N_NODES*FOUT*4u)            // 8192 f32
#define GKEY_OFF (T_OFF + N_NODES*4u)                 // 1 u32 (monotone key)
#define YT_OFF   (GKEY_OFF + 512u)                    // 144*8192 bf16 = 2.36 MB
#define P_OFF    (YT_OFF + (size_t)NPAD*N_NODES*2u)   // 8*8192*144 f32 = 37.7 MB
#define ADJP_OFF (P_OFF + (size_t)NSPLIT*N_NODES*NPAD*4u)  // 8192*128 B = 8 MB

__device__ __forceinline__ unsigned short f2bf(float f) {
  unsigned int u = __float_as_uint(f);
  unsigned int r = (u + 0x7FFFu + ((u >> 16) & 1u)) >> 16;   // RNE
  return (unsigned short)r;
}

// monotone float<->uint key for atomicMax over signed floats
__device__ __forceinline__ unsigned fkey(float f) {
  unsigned b = __float_as_uint(f);
  return (b & 0x80000000u) ? ~b : (b | 0x80000000u);
}
__device__ __forceinline__ float fkey_dec(unsigned k) {
  return __uint_as_float((k & 0x80000000u) ? (k & 0x7FFFFFFFu) : ~k);
}

// ---- K0: pack adj int32 0/1 -> 1 bit/col. bit j of u64 G <-> col G*64+j ---
// grid.y replicates identical work (instrumentation) — blockIdx.y ignored.
__global__ __launch_bounds__(256) void k0_pack(const int* __restrict__ adj,
    unsigned long long* __restrict__ adjP, unsigned* __restrict__ gkey) {
  if (blockIdx.x == 0 && threadIdx.x == 0) gkey[0] = 0u;  // key(-max)
  const int lane = threadIdx.x & 63, w = threadIdx.x >> 6;
  const int row = blockIdx.x * 4 + w;
  const int* src = adj + (size_t)row * N_NODES;
  unsigned long long mine = 0;
  for (int h = 0; h < 2; ++h) {
    #pragma unroll 16
    for (int g = 0; g < 64; ++g) {
      int v = src[h * 4096 + g * 64 + lane];
      unsigned long long m = __ballot(v != 0);
      if (lane == g) mine = m;
    }
    adjP[(size_t)row * 128 + h * 64 + lane] = mine;
  }
}

// ---- K1: x = input @ W_fc + b_fc ; fused t = x.w_an + b_an, gmax ----------
__global__ __launch_bounds__(256) void k1_fc(const float* __restrict__ in,
    const float* __restrict__ Wfc, const float* __restrict__ bfc,
    const float* __restrict__ wan, const float* __restrict__ ban,
    float* __restrict__ x, float* __restrict__ t, unsigned* __restrict__ gkey) {
  __shared__ float sm[16 * FIN];
  __shared__ float part[2][16];
  __shared__ float tval[16];
  const int tid = threadIdx.x;
  const int r0  = blockIdx.x * 16;
  const float4* gin = reinterpret_cast<const float4*>(in + (size_t)r0 * FIN);
  float4* sm4 = reinterpret_cast<float4*>(sm);
  #pragma unroll
  for (int i = 0; i < 4; i++) sm4[i * 256 + tid] = gin[i * 256 + tid];
  __syncthreads();
  const int d = tid & 127, g = tid >> 7;
  const float bias = bfc[d];
  float acc[8];
  #pragma unroll
  for (int r = 0; r < 8; r++) acc[r] = bias;
  const float4* s4 = reinterpret_cast<const float4*>(sm);
  for (int k = 0; k < FIN; k += 4) {
    float w0 = Wfc[(k + 0) * FOUT + d];
    float w1 = Wfc[(k + 1) * FOUT + d];
    float w2 = Wfc[(k + 2) * FOUT + d];
    float w3 = Wfc[(k + 3) * FOUT + d];
    #pragma unroll
    for (int r = 0; r < 8; r++) {
      float4 iv = s4[((g * 8 + r) * FIN + k) >> 2];
      acc[r] = fmaf(iv.x, w0, acc[r]);
      acc[r] = fmaf(iv.y, w1, acc[r]);
      acc[r] = fmaf(iv.z, w2, acc[r]);
      acc[r] = fmaf(iv.w, w3, acc[r]);
    }
  }
  #pragma unroll
  for (int r = 0; r < 8; r++)
    x[(size_t)(r0 + g * 8 + r) * FOUT + d] = acc[r];

  // fused attention scalar t = x . w_an (+ b_an), reduced over d
  const float wv = wan[d];
  const int lane = tid & 63, half = (tid >> 6) & 1;
  #pragma unroll
  for (int r = 0; r < 8; r++) {
    float p = acc[r] * wv;
    #pragma unroll
    for (int m = 1; m < 64; m <<= 1) p += __shfl_xor(p, m);
    if (lane == 0) part[half][g * 8 + r] = p;
  }
  __syncthreads();
  if (tid < 16) {
    const float tv = part[0][tid] + part[1][tid] + ban[0];
    t[r0 + tid] = tv;
    tval[tid] = tv;
  }
  __syncthreads();
  if (tid == 0) {
    float m = tval[0];
    #pragma unroll
    for (int i = 1; i < 16; i++) m = fmaxf(m, tval[i]);
    atomicMax(gkey, fkey(m));
  }
}

// ---- K4: build Yf in MFMA B-fragment order via LDS transpose --------------
__global__ __launch_bounds__(256) void k4_y(const float* __restrict__ x,
    const float* __restrict__ t, const unsigned* __restrict__ gkey,
    unsigned short* __restrict__ Yf) {
  __shared__ unsigned short sm[NPAD * 64];
  const int tid = threadIdx.x, lane = tid & 63, w = tid >> 6;
  const int jj = lane, j = blockIdx.x * 64 + jj;
  const float gm = fkey_dec(gkey[0]);
  const float e = expf(t[j] - gm);
  const float4* x4 = reinterpret_cast<const float4*>(x + (size_t)j * FOUT + w * 32);
  #pragma unroll
  for (int dd = 0; dd < 8; dd++) {
    float4 xv = x4[dd];
    const int c = w * 32 + dd * 4;
    sm[(c + 0) * 64 + jj] = f2bf(e * xv.x);
    sm[(c + 1) * 64 + jj] = f2bf(e * xv.y);
    sm[(c + 2) * 64 + jj] = f2bf(e * xv.z);
    sm[(c + 3) * 64 + jj] = f2bf(e * xv.w);
  }
  #pragma unroll
  for (int i = 0; i < 4; i++) {     // cols 128..143: e in col 128, pads 0
    const int c = 128 + w * 4 + i;
    sm[c * 64 + jj] = (c == 128) ? f2bf(e) : (unsigned short)0;
  }
  __syncthreads();
  for (int c5 = w; c5 < 18; c5 += 4) {
    const int wnd = c5 / 9, nf = c5 % 9;
    const int srcIdx = (nf * 16 + (lane & 15)) * 64 + wnd * 32 + (lane >> 4) * 8;
    bf16x8 v = *reinterpret_cast<const bf16x8*>(&sm[srcIdx]);
    const size_t Wg = (size_t)blockIdx.x * 2 + wnd;
    *reinterpret_cast<bf16x8*>(Yf + (Wg * 9 + nf) * 512 + lane * 8) = v;
  }
}

// ---- K5: P[s] = A[:, chunk_s] @ Y[chunk_s, :]   (bf16 MFMA, split-K) ------
// BM=128 (8 waves x 16 rows), BN=144 (9 n-frags). No LDS, no barriers.
// grid.z replicates identical work (instrumentation) — blockIdx.z ignored.
__global__ __launch_bounds__(512, 4) void k5_gemm(
    const unsigned long long* __restrict__ adjP,
    const unsigned short* __restrict__ Yf, float* __restrict__ P) {
  const int tid  = threadIdx.x;
  const int lane = tid & 63, w = tid >> 6;          // w = 0..7
  const int bm = blockIdx.x, s = blockIdx.y;
  const int q  = lane >> 4, r = lane & 15;
  const int row_g = bm * 128 + w * 16 + r;
  const unsigned long long* ap = adjP + (size_t)row_g * 128 + s * 16;
  const unsigned short* bbase = Yf + (size_t)s * 32 * 9 * 512 + lane * 8;
  const int qs = q * 8;

  f32x4 acc[9];
  #pragma unroll
  for (int nf = 0; nf < 9; nf++) acc[nf] = (f32x4){0.f, 0.f, 0.f, 0.f};

  // byte b_ (bits e=0..7 = A elems k=qs+e) -> bf16 frag {0,1}; 9 MFMAs
#define MFMA_WIN(b_, woff_) { \
    bf16x8 bv[9]; \
    const unsigned short* p_ = bbase + (size_t)(woff_) * (9 * 512); \
    _Pragma("unroll") \
    for (int nf = 0; nf < 9; nf++) \
      bv[nf] = *reinterpret_cast<const bf16x8*>(p_ + nf * 512); \
    union { bf16x8 v; unsigned int u[4]; } af; \
    _Pragma("unroll") \
    for (int i2 = 0; i2 < 4; i2++) { \
      const unsigned bq = (b_) >> (2 * i2); \
      af.u[i2] = ((bq & 1u) ? 0x3F80u : 0u) | ((bq & 2u) ? 0x3F800000u : 0u); \
    } \
    _Pragma("unroll") \
    for (int nf = 0; nf < 9; nf++) \
      acc[nf] = __builtin_amdgcn_mfma_f32_16x16x32_bf16(af.v, bv[nf], acc[nf], 0, 0, 0); \
  }

  unsigned long long Ac = ap[0];
  unsigned long long An = ap[1];
  for (int t = 0; t < 16; ++t) {
    const unsigned lo = (unsigned)Ac, hi = (unsigned)(Ac >> 32);
    MFMA_WIN(((lo >> qs) & 0xFFu), 2 * t);
    MFMA_WIN(((hi >> qs) & 0xFFu), 2 * t + 1);
    Ac = An;
    if (t < 14) An = ap[t + 2];
  }
#undef MFMA_WIN

  float* Pp = P + (size_t)s * N_NODES * NPAD;
  const int colb = lane & 15;
  #pragma unroll
  for (int nf = 0; nf < 9; nf++) {
    // nf==8 covers cols 128..143; only col 128 (Z) is ever read — skip pads.
    if (nf == 8 && colb != 0) continue;
    #pragma unroll
    for (int rr = 0; rr < 4; rr++) {
      const int grow = bm * 128 + w * 16 + q * 4 + rr; // C/D: row=(lane>>4)*4+rr
      Pp[(size_t)grow * NPAD + nf * 16 + colb] = acc[nf][rr];
    }
  }
}

// ---- K6: reduce split-K, divide, residual, ELU ----------------------------
__global__ __launch_bounds__(256) void k6_fin(const float* __restrict__ P,
    const float* __restrict__ x, float* __restrict__ out) {
  const int gid = blockIdx.x * 256 + threadIdx.x;
  const int i = gid >> 7, d = gid & 127;
  const size_t base = (size_t)i * NPAD;
  float num = 0.f, Z = 0.f;
  #pragma unroll
  for (int s = 0; s < NSPLIT; s++) {
    num += P[(size_t)s * N_NODES * NPAD + base + d];
    Z   += P[(size_t)s * N_NODES * NPAD + base + 128];
  }
  const float agg = (Z > 0.f) ? num / Z : 0.f;   // empty row never occurs here
  const float v = x[(size_t)i * FOUT + d] + agg;
  out[gid] = (v > 0.f) ? v : expm1f(v);
}

extern "C" void kernel_launch(void* const* d_in, const int* in_sizes, int n_in,
                              void* d_out, int out_size, void* d_ws, size_t ws_size,
                              hipStream_t stream) {
  const float* input = (const float*)d_in[0];
  const int*   adj   = (const int*)d_in[1];
  const float* Wfc   = (const float*)d_in[2];
  const float* bfc   = (const float*)d_in[3];
  // d_in[4], d_in[5] (w_ax, b_ax) cancel in the row softmax — unused.
  const float* wan   = (const float*)d_in[6];
  const float* ban   = (const float*)d_in[7];

  char* ws = (char*)d_ws;
  float*              x    = (float*)(ws + X_OFF);
  float*              t    = (float*)(ws + T_OFF);
  unsigned*           gkey = (unsigned*)(ws + GKEY_OFF);
  unsigned short*     Yf   = (unsigned short*)(ws + YT_OFF);
  float*              P    = (float*)(ws + P_OFF);
  unsigned long long* adjP = (unsigned long long*)(ws + ADJP_OFF);
  float*              out  = (float*)d_out;

  // INSTRUMENTATION: k0 x2 (grid.y), k5 x4 (grid.z) — identical writes.
  k0_pack<<<dim3(2048, 2),       dim3(256), 0, stream>>>(adj, adjP, gkey);
  k1_fc  <<<dim3(512),           dim3(256), 0, stream>>>(input, Wfc, bfc, wan, ban,
                                                         x, t, gkey);
  k4_y   <<<dim3(128),           dim3(256), 0, stream>>>(x, t, gkey, Yf);
  k5_gemm<<<dim3(64, NSPLIT, 4), dim3(512), 0, stream>>>(adjP, Yf, P);
  k6_fin <<<dim3(4096),          dim3(256), 0, stream>>>(P, x, out);
}

// Round 9
// 439.158 us; speedup vs baseline: 1.4342x; 1.4342x over previous
//
#include <hip/hip_runtime.h>
#include <hip/hip_bf16.h>
#include <math.h>

// ---------------------------------------------------------------------------
// GraphAttentionLayer on MI355X.
// Math: softmax over (s_i + t_j) masked by adj  ==> s_i cancels row-wise.
//   e_j   = exp(t_j - gmax)
//   agg_i = (A @ (e*x))_i / (A @ e)_i          (A = adj as 0/1)
//   out   = elu(x + agg)
// => dense bf16 MFMA GEMM  A[8192x8192] @ Y[8192x144], split-K=8.
// k0 packs adj to 1 bit/entry (268MB stream ~ peak BW) in MFMA bit order.
// k1 computes x = in@W+b AND t = x.w_an + b_an (fused; atomicMax key -> gmax).
// k4 builds Yf (B-fragment order).
// k5 (R9): M=64 rows/wave (4 A-frags reuse each B batch in regs) -> B
//   cache traffic 1.21GB -> 302MB, the R8-measured bottleneck. No LDS,
//   no barriers. k6 reduces split-K + residual + ELU.
// ---------------------------------------------------------------------------

using f32x4  = __attribute__((ext_vector_type(4))) float;
using bf16x8 = __attribute__((ext_vector_type(8))) short;

#define N_NODES 8192
#define FIN     256
#define FOUT    128
#define NPAD    144
#define NSPLIT  8
#define KCHUNK  (N_NODES / NSPLIT)   // 1024

// workspace layout (bytes)
#define X_OFF    0u                                   // 8192*128 f32  = 4 MB
#define T_OFF    (X_OFF + N_NODES*FOUT*4u)            // 8192 f32
#define GKEY_OFF (T_OFF + N_NODES*4u)                 // 1 u32 (monotone key)
#define YT_OFF   (GKEY_OFF + 512u)                    // 144*8192 bf16 = 2.36 MB
#define P_OFF    (YT_OFF + (size_t)NPAD*N_NODES*2u)   // 8*8192*144 f32 = 37.7 MB
#define ADJP_OFF (P_OFF + (size_t)NSPLIT*N_NODES*NPAD*4u)  // 8192*128 B = 8 MB

__device__ __forceinline__ unsigned short f2bf(float f) {
  unsigned int u = __float_as_uint(f);
  unsigned int r = (u + 0x7FFFu + ((u >> 16) & 1u)) >> 16;   // RNE
  return (unsigned short)r;
}

// monotone float<->uint key for atomicMax over signed floats
__device__ __forceinline__ unsigned fkey(float f) {
  unsigned b = __float_as_uint(f);
  return (b & 0x80000000u) ? ~b : (b | 0x80000000u);
}
__device__ __forceinline__ float fkey_dec(unsigned k) {
  return __uint_as_float((k & 0x80000000u) ? (k & 0x7FFFFFFFu) : ~k);
}

// ---- K0: pack adj int32 0/1 -> 1 bit/col. bit j of u64 G <-> col G*64+j ---
__global__ __launch_bounds__(256) void k0_pack(const int* __restrict__ adj,
    unsigned long long* __restrict__ adjP, unsigned* __restrict__ gkey) {
  if (blockIdx.x == 0 && threadIdx.x == 0) gkey[0] = 0u;  // key(-max)
  const int lane = threadIdx.x & 63, w = threadIdx.x >> 6;
  const int row = blockIdx.x * 4 + w;
  const int* src = adj + (size_t)row * N_NODES;
  unsigned long long mine = 0;
  for (int h = 0; h < 2; ++h) {
    #pragma unroll 16
    for (int g = 0; g < 64; ++g) {
      int v = src[h * 4096 + g * 64 + lane];
      unsigned long long m = __ballot(v != 0);
      if (lane == g) mine = m;
    }
    adjP[(size_t)row * 128 + h * 64 + lane] = mine;
  }
}

// ---- K1: x = input @ W_fc + b_fc ; fused t = x.w_an + b_an, gmax ----------
__global__ __launch_bounds__(256) void k1_fc(const float* __restrict__ in,
    const float* __restrict__ Wfc, const float* __restrict__ bfc,
    const float* __restrict__ wan, const float* __restrict__ ban,
    float* __restrict__ x, float* __restrict__ t, unsigned* __restrict__ gkey) {
  __shared__ float sm[16 * FIN];
  __shared__ float part[2][16];
  __shared__ float tval[16];
  const int tid = threadIdx.x;
  const int r0  = blockIdx.x * 16;
  const float4* gin = reinterpret_cast<const float4*>(in + (size_t)r0 * FIN);
  float4* sm4 = reinterpret_cast<float4*>(sm);
  #pragma unroll
  for (int i = 0; i < 4; i++) sm4[i * 256 + tid] = gin[i * 256 + tid];
  __syncthreads();
  const int d = tid & 127, g = tid >> 7;
  const float bias = bfc[d];
  float acc[8];
  #pragma unroll
  for (int r = 0; r < 8; r++) acc[r] = bias;
  const float4* s4 = reinterpret_cast<const float4*>(sm);
  for (int k = 0; k < FIN; k += 4) {
    float w0 = Wfc[(k + 0) * FOUT + d];
    float w1 = Wfc[(k + 1) * FOUT + d];
    float w2 = Wfc[(k + 2) * FOUT + d];
    float w3 = Wfc[(k + 3) * FOUT + d];
    #pragma unroll
    for (int r = 0; r < 8; r++) {
      float4 iv = s4[((g * 8 + r) * FIN + k) >> 2];
      acc[r] = fmaf(iv.x, w0, acc[r]);
      acc[r] = fmaf(iv.y, w1, acc[r]);
      acc[r] = fmaf(iv.z, w2, acc[r]);
      acc[r] = fmaf(iv.w, w3, acc[r]);
    }
  }
  #pragma unroll
  for (int r = 0; r < 8; r++)
    x[(size_t)(r0 + g * 8 + r) * FOUT + d] = acc[r];

  // fused attention scalar t = x . w_an (+ b_an), reduced over d
  const float wv = wan[d];
  const int lane = tid & 63, half = (tid >> 6) & 1;
  #pragma unroll
  for (int r = 0; r < 8; r++) {
    float p = acc[r] * wv;
    #pragma unroll
    for (int m = 1; m < 64; m <<= 1) p += __shfl_xor(p, m);
    if (lane == 0) part[half][g * 8 + r] = p;
  }
  __syncthreads();
  if (tid < 16) {
    const float tv = part[0][tid] + part[1][tid] + ban[0];
    t[r0 + tid] = tv;
    tval[tid] = tv;
  }
  __syncthreads();
  if (tid == 0) {
    float m = tval[0];
    #pragma unroll
    for (int i = 1; i < 16; i++) m = fmaxf(m, tval[i]);
    atomicMax(gkey, fkey(m));
  }
}

// ---- K4: build Yf in MFMA B-fragment order via LDS transpose --------------
__global__ __launch_bounds__(256) void k4_y(const float* __restrict__ x,
    const float* __restrict__ t, const unsigned* __restrict__ gkey,
    unsigned short* __restrict__ Yf) {
  __shared__ unsigned short sm[NPAD * 64];
  const int tid = threadIdx.x, lane = tid & 63, w = tid >> 6;
  const int jj = lane, j = blockIdx.x * 64 + jj;
  const float gm = fkey_dec(gkey[0]);
  const float e = expf(t[j] - gm);
  const float4* x4 = reinterpret_cast<const float4*>(x + (size_t)j * FOUT + w * 32);
  #pragma unroll
  for (int dd = 0; dd < 8; dd++) {
    float4 xv = x4[dd];
    const int c = w * 32 + dd * 4;
    sm[(c + 0) * 64 + jj] = f2bf(e * xv.x);
    sm[(c + 1) * 64 + jj] = f2bf(e * xv.y);
    sm[(c + 2) * 64 + jj] = f2bf(e * xv.z);
    sm[(c + 3) * 64 + jj] = f2bf(e * xv.w);
  }
  #pragma unroll
  for (int i = 0; i < 4; i++) {     // cols 128..143: e in col 128, pads 0
    const int c = 128 + w * 4 + i;
    sm[c * 64 + jj] = (c == 128) ? f2bf(e) : (unsigned short)0;
  }
  __syncthreads();
  for (int c5 = w; c5 < 18; c5 += 4) {
    const int wnd = c5 / 9, nf = c5 % 9;
    const int srcIdx = (nf * 16 + (lane & 15)) * 64 + wnd * 32 + (lane >> 4) * 8;
    bf16x8 v = *reinterpret_cast<const bf16x8*>(&sm[srcIdx]);
    const size_t Wg = (size_t)blockIdx.x * 2 + wnd;
    *reinterpret_cast<bf16x8*>(Yf + (Wg * 9 + nf) * 512 + lane * 8) = v;
  }
}

// ---- K5: P[s] = A[:, chunk_s] @ Y[chunk_s, :]   (bf16 MFMA, split-K) ------
// BM=256 = 4 waves x 64 rows (M=64/wave: 4 A-frags reuse each B batch).
// No LDS, no barriers. A: u64 bitmask/frag/64k-tile (L2-hot), VALU expand.
// B: JIT 9-frag batch per 32-k window, shared by 4 MFMA groups.
__global__ __launch_bounds__(256, 2) void k5_gemm(
    const unsigned long long* __restrict__ adjP,
    const unsigned short* __restrict__ Yf, float* __restrict__ P) {
  const int tid  = threadIdx.x;
  const int lane = tid & 63, w = tid >> 6;          // w = 0..3
  const int bm = blockIdx.x, s = blockIdx.y;
  const int q  = lane >> 4, r = lane & 15;
  const int rowbase = bm * 256 + w * 64 + r;        // + f*16 per A-frag
  const unsigned long long* ap = adjP + (size_t)rowbase * 128 + s * 16;
  // frag f's bitmask row stride: 16 rows * 128 u64 = 2048 u64
  const unsigned short* bbase = Yf + (size_t)s * 32 * 9 * 512 + lane * 8;
  const int qs = q * 8;

  f32x4 acc[4][9];
  #pragma unroll
  for (int f = 0; f < 4; f++)
    #pragma unroll
    for (int nf = 0; nf < 9; nf++) acc[f][nf] = (f32x4){0.f, 0.f, 0.f, 0.f};

  // One 32-k window: 9 B-frag loads shared by 4 A-frags (36 MFMAs).
#define MFMA_WIN(Asrc_, shift_, woff_) { \
    bf16x8 bv[9]; \
    const unsigned short* p_ = bbase + (size_t)(woff_) * (9 * 512); \
    _Pragma("unroll") \
    for (int nf = 0; nf < 9; nf++) \
      bv[nf] = *reinterpret_cast<const bf16x8*>(p_ + nf * 512); \
    union { bf16x8 v; unsigned int u[4]; } af[4]; \
    _Pragma("unroll") \
    for (int f = 0; f < 4; f++) { \
      const unsigned b8 = (unsigned)((Asrc_[f]) >> (shift_)) >> qs; \
      _Pragma("unroll") \
      for (int i2 = 0; i2 < 4; i2++) { \
        const unsigned bq = b8 >> (2 * i2); \
        af[f].u[i2] = ((bq & 1u) ? 0x3F80u : 0u) | ((bq & 2u) ? 0x3F800000u : 0u); \
      } \
    } \
    _Pragma("unroll") \
    for (int f = 0; f < 4; f++) \
      _Pragma("unroll") \
      for (int nf = 0; nf < 9; nf++) \
        acc[f][nf] = __builtin_amdgcn_mfma_f32_16x16x32_bf16(af[f].v, bv[nf], \
                                                             acc[f][nf], 0, 0, 0); \
  }

  unsigned long long Ac[4], An[4];
  #pragma unroll
  for (int f = 0; f < 4; f++) Ac[f] = ap[(size_t)f * 2048];
  #pragma unroll
  for (int f = 0; f < 4; f++) An[f] = ap[(size_t)f * 2048 + 1];

  for (int t = 0; t < 16; ++t) {
    MFMA_WIN(Ac, 0,  2 * t);       // bits 0..31  (k = t*64 .. +31)
    MFMA_WIN(Ac, 32, 2 * t + 1);   // bits 32..63 (k = t*64+32 .. +63)
    #pragma unroll
    for (int f = 0; f < 4; f++) Ac[f] = An[f];
    if (t < 14) {
      #pragma unroll
      for (int f = 0; f < 4; f++) An[f] = ap[(size_t)f * 2048 + t + 2];
    }
  }
#undef MFMA_WIN

  float* Pp = P + (size_t)s * N_NODES * NPAD;
  const int colb = lane & 15;
  #pragma unroll
  for (int f = 0; f < 4; f++) {
    #pragma unroll
    for (int nf = 0; nf < 9; nf++) {
      // nf==8 covers cols 128..143; only col 128 (Z) is read — skip pads.
      if (nf == 8 && colb != 0) continue;
      #pragma unroll
      for (int rr = 0; rr < 4; rr++) {
        const int grow = bm * 256 + w * 64 + f * 16 + q * 4 + rr;
        Pp[(size_t)grow * NPAD + nf * 16 + colb] = acc[f][nf][rr];
      }
    }
  }
}

// ---- K6: reduce split-K, divide, residual, ELU ----------------------------
__global__ __launch_bounds__(256) void k6_fin(const float* __restrict__ P,
    const float* __restrict__ x, float* __restrict__ out) {
  const int gid = blockIdx.x * 256 + threadIdx.x;
  const int i = gid >> 7, d = gid & 127;
  const size_t base = (size_t)i * NPAD;
  float num = 0.f, Z = 0.f;
  #pragma unroll
  for (int s = 0; s < NSPLIT; s++) {
    num += P[(size_t)s * N_NODES * NPAD + base + d];
    Z   += P[(size_t)s * N_NODES * NPAD + base + 128];
  }
  const float agg = (Z > 0.f) ? num / Z : 0.f;   // empty row never occurs here
  const float v = x[(size_t)i * FOUT + d] + agg;
  out[gid] = (v > 0.f) ? v : expm1f(v);
}

extern "C" void kernel_launch(void* const* d_in, const int* in_sizes, int n_in,
                              void* d_out, int out_size, void* d_ws, size_t ws_size,
                              hipStream_t stream) {
  const float* input = (const float*)d_in[0];
  const int*   adj   = (const int*)d_in[1];
  const float* Wfc   = (const float*)d_in[2];
  const float* bfc   = (const float*)d_in[3];
  // d_in[4], d_in[5] (w_ax, b_ax) cancel in the row softmax — unused.
  const float* wan   = (const float*)d_in[6];
  const float* ban   = (const float*)d_in[7];

  char* ws = (char*)d_ws;
  float*              x    = (float*)(ws + X_OFF);
  float*              t    = (float*)(ws + T_OFF);
  unsigned*           gkey = (unsigned*)(ws + GKEY_OFF);
  unsigned short*     Yf   = (unsigned short*)(ws + YT_OFF);
  float*              P    = (float*)(ws + P_OFF);
  unsigned long long* adjP = (unsigned long long*)(ws + ADJP_OFF);
  float*              out  = (float*)d_out;

  k0_pack<<<dim3(2048),       dim3(256), 0, stream>>>(adj, adjP, gkey);
  k1_fc  <<<dim3(512),        dim3(256), 0, stream>>>(input, Wfc, bfc, wan, ban,
                                                      x, t, gkey);
  k4_y   <<<dim3(128),        dim3(256), 0, stream>>>(x, t, gkey, Yf);
  k5_gemm<<<dim3(32, NSPLIT), dim3(256), 0, stream>>>(adjP, Yf, P);
  k6_fin <<<dim3(4096),       dim3(256), 0, stream>>>(P, x, out);
}